// Round 1
// baseline (284.502 us; speedup 1.0000x reference)
//
#include <hip/hip_runtime.h>
#include <hip/hip_bf16.h>

typedef __attribute__((ext_vector_type(8))) short s8v;    // 8 bf16
typedef __attribute__((ext_vector_type(4))) float f4v;    // 4 fp32

#define LOG2E 1.44269504088896340736f

__device__ __forceinline__ void g2lds16(const void* g, void* l) {
  __builtin_amdgcn_global_load_lds(
      (__attribute__((address_space(1))) void*)(g),
      (__attribute__((address_space(3))) void*)(l), 16, 0, 0);
}

// ---------------- K0a: x fp32 -> bf16 ----------------
__global__ void k_cvt_x(const float* __restrict__ x, __hip_bfloat16* __restrict__ xb) {
  int i = (blockIdx.x * 256 + threadIdx.x) * 4;
  float4 v = *(const float4*)(x + i);
  __hip_bfloat16 o[4] = {__float2bfloat16(v.x), __float2bfloat16(v.y),
                         __float2bfloat16(v.z), __float2bfloat16(v.w)};
  *(uint2*)(xb + i) = *(const uint2*)(o);
}

// ---------------- K0b: W [1024,3072] fp32 -> Wt [3072,1024] bf16 ----------------
__global__ void k_transpose_w(const float* __restrict__ W, __hip_bfloat16* __restrict__ Wt) {
  __shared__ float tile[32][33];
  int c0 = blockIdx.x * 32;   // over 3072
  int r0 = blockIdx.y * 32;   // over 1024
  int tr = threadIdx.x >> 5;  // 0..7
  int tc = threadIdx.x & 31;
#pragma unroll
  for (int i = 0; i < 32; i += 8)
    tile[tr + i][tc] = W[(size_t)(r0 + tr + i) * 3072 + c0 + tc];
  __syncthreads();
#pragma unroll
  for (int i = 0; i < 32; i += 8)
    Wt[(size_t)(c0 + tr + i) * 1024 + r0 + tc] = __float2bfloat16(tile[tc][tr + i]);
}

// ---------------- K1: GEMM  Y[4096,3072] = A[4096,1024] @ Wt^T, + bias, bf16 out ----
__global__ __launch_bounds__(256) void k_gemm(const __hip_bfloat16* __restrict__ A,
                                              const __hip_bfloat16* __restrict__ Bt,
                                              const float* __restrict__ bias,
                                              __hip_bfloat16* __restrict__ Y) {
  __shared__ __align__(16) __hip_bfloat16 As[128 * 32];
  __shared__ __align__(16) __hip_bfloat16 Bs[128 * 32];
  const int tid = threadIdx.x;
  const int lane = tid & 63, wave = tid >> 6;
  const int m0 = blockIdx.y * 128, n0 = blockIdx.x * 128;
  const int wm = (wave & 1) * 64, wn = (wave >> 1) * 64;
  const int lrow = lane & 15, lk = (lane >> 4) * 8;

  f4v acc[4][4] = {};

  for (int k0 = 0; k0 < 1024; k0 += 32) {
#pragma unroll
    for (int c = 0; c < 2; ++c) {
      int e = c * 2048 + tid * 8;
      int row = e >> 5, col = e & 31;
      g2lds16(A + (size_t)(m0 + row) * 1024 + k0 + col, As + e);
      g2lds16(Bt + (size_t)(n0 + row) * 1024 + k0 + col, Bs + e);
    }
    __syncthreads();
    s8v af[4], bfr[4];
#pragma unroll
    for (int mi = 0; mi < 4; ++mi) af[mi] = *(const s8v*)(As + (wm + mi * 16 + lrow) * 32 + lk);
#pragma unroll
    for (int ni = 0; ni < 4; ++ni) bfr[ni] = *(const s8v*)(Bs + (wn + ni * 16 + lrow) * 32 + lk);
#pragma unroll
    for (int mi = 0; mi < 4; ++mi)
#pragma unroll
      for (int ni = 0; ni < 4; ++ni)
        acc[mi][ni] = __builtin_amdgcn_mfma_f32_16x16x32_bf16(af[mi], bfr[ni], acc[mi][ni], 0, 0, 0);
    __syncthreads();
  }

#pragma unroll
  for (int mi = 0; mi < 4; ++mi) {
    int r = m0 + wm + mi * 16 + (lane >> 4) * 4;
#pragma unroll
    for (int ni = 0; ni < 4; ++ni) {
      int c = n0 + wn + ni * 16 + lrow;
      float bv = bias[c];
#pragma unroll
      for (int reg = 0; reg < 4; ++reg)
        Y[(size_t)(r + reg) * 3072 + c] = __float2bfloat16(acc[mi][ni][reg] + bv);
    }
  }
}

// ---------------- K2: gather y -> Q [b,h,t,d], K [b,h,t,d], Vt [b,h,d,t] ----------
// q[b,h,t,d] = yflat[s*4194304 + b*2097152 + t*1024 + d*16 + h]
__global__ void k_gather(const __hip_bfloat16* __restrict__ y,
                         __hip_bfloat16* __restrict__ Q,
                         __hip_bfloat16* __restrict__ K,
                         __hip_bfloat16* __restrict__ Vt) {
  __shared__ __align__(16) __hip_bfloat16 lds[16 * 1028];  // rows padded 1024->1028
  int bx = blockIdx.x;
  int s = bx >> 8, rem = bx & 255, b = rem >> 7, tc = rem & 127;
  const __hip_bfloat16* src = y + (size_t)s * 4194304 + (size_t)b * 2097152 + (size_t)tc * 16384;
  for (int c = threadIdx.x; c < 4096; c += 256) {  // 4-bf16 (8B) chunks
    int tt = c >> 8, jc = c & 255;
    *(uint2*)(lds + tt * 1028 + jc * 4) = *(const uint2*)(src + tt * 1024 + jc * 4);
  }
  __syncthreads();
  size_t hb = (size_t)b * 16 * 131072;
  if (s < 2) {
    __hip_bfloat16* dst = (s == 0) ? Q : K;
    for (int e = threadIdx.x; e < 16384; e += 256) {
      int h = e >> 10, r = e & 1023;
      int tt = r >> 6, d = r & 63;
      dst[hb + (size_t)h * 131072 + (size_t)(tc * 16 + tt) * 64 + d] = lds[tt * 1028 + d * 16 + h];
    }
  } else {
    for (int e = threadIdx.x; e < 16384; e += 256) {
      int h = e >> 10, r = e & 1023;
      int d = r >> 4, tt = r & 15;
      Vt[hb + (size_t)h * 131072 + (size_t)d * 2048 + tc * 16 + tt] = lds[tt * 1028 + d * 16 + h];
    }
  }
}

// ---------------- K3: causal flash attention ----------------
// Q,K: [bh][2048][64] bf16; Vt: [bh][64][2048] bf16; out: [b][2048][1024] fp32
__global__ __launch_bounds__(256) void k_attn(const __hip_bfloat16* __restrict__ Q,
                                              const __hip_bfloat16* __restrict__ K,
                                              const __hip_bfloat16* __restrict__ Vt,
                                              float* __restrict__ out) {
  __shared__ __align__(16) __hip_bfloat16 Qs[64 * 64];
  __shared__ __align__(16) __hip_bfloat16 Ks[64 * 64];
  __shared__ __align__(16) __hip_bfloat16 Vs[64 * 64];       // Vs[d][s]
  __shared__ __align__(16) __hip_bfloat16 Ps[4][16 * 80];    // per-wave P strip, stride 80

  const int tid = threadIdx.x;
  const int lane = tid & 63, w = tid >> 6;
  const int lrow = lane & 15, quad = lane >> 4;
  const int qi = gridDim.x - 1 - blockIdx.x;   // heavy (large-qi) blocks first
  const int bh = blockIdx.y;

  const __hip_bfloat16* Qp = Q + (size_t)bh * 131072 + (size_t)qi * 4096;
  const __hip_bfloat16* Kp = K + (size_t)bh * 131072;
  const __hip_bfloat16* Vp = Vt + (size_t)bh * 131072;

#pragma unroll
  for (int c = 0; c < 2; ++c) {
    int off = c * 2048 + tid * 8;
    g2lds16(Qp + off, Qs + off);
  }
  __syncthreads();

  s8v aq0 = *(const s8v*)(Qs + (w * 16 + lrow) * 64 + quad * 8);
  s8v aq1 = *(const s8v*)(Qs + (w * 16 + lrow) * 64 + 32 + quad * 8);

  f4v o[4] = {};
  float m_r[4], l_r[4];
#pragma unroll
  for (int r = 0; r < 4; ++r) { m_r[r] = -INFINITY; l_r[r] = 0.f; }
  const float scale = 0.125f;

  for (int j = 0; j <= qi; ++j) {
    __syncthreads();  // previous iteration's Ks/Vs reads complete
#pragma unroll
    for (int c = 0; c < 2; ++c) {
      int off = c * 2048 + tid * 8;
      g2lds16(Kp + (size_t)j * 4096 + off, Ks + off);
      int d = off >> 6, cb = off & 63;
      g2lds16(Vp + (size_t)d * 2048 + j * 64 + cb, Vs + off);
    }
    __syncthreads();

    f4v s[4];
#pragma unroll
    for (int nt = 0; nt < 4; ++nt) {
      s8v bk0 = *(const s8v*)(Ks + (nt * 16 + lrow) * 64 + quad * 8);
      s8v bk1 = *(const s8v*)(Ks + (nt * 16 + lrow) * 64 + 32 + quad * 8);
      f4v z = {};
      z = __builtin_amdgcn_mfma_f32_16x16x32_bf16(aq0, bk0, z, 0, 0, 0);
      z = __builtin_amdgcn_mfma_f32_16x16x32_bf16(aq1, bk1, z, 0, 0, 0);
      s[nt] = z;
    }

    float p[4][4];
    bool diag = (j == qi);
#pragma unroll
    for (int nt = 0; nt < 4; ++nt)
#pragma unroll
      for (int reg = 0; reg < 4; ++reg) {
        float v = s[nt][reg] * scale;
        if (diag && (nt * 16 + lrow) > (w * 16 + quad * 4 + reg)) v = -INFINITY;
        p[nt][reg] = v;
      }

#pragma unroll
    for (int reg = 0; reg < 4; ++reg) {
      float mx = fmaxf(fmaxf(p[0][reg], p[1][reg]), fmaxf(p[2][reg], p[3][reg]));
#pragma unroll
      for (int off = 1; off < 16; off <<= 1) mx = fmaxf(mx, __shfl_xor(mx, off));
      float mn = fmaxf(m_r[reg], mx);
      float alpha = exp2f((m_r[reg] - mn) * LOG2E);
      m_r[reg] = mn;
      float rs = 0.f;
#pragma unroll
      for (int nt = 0; nt < 4; ++nt) {
        float pe = exp2f((p[nt][reg] - mn) * LOG2E);
        p[nt][reg] = pe;
        rs += pe;
      }
#pragma unroll
      for (int off = 1; off < 16; off <<= 1) rs += __shfl_xor(rs, off);
      l_r[reg] = l_r[reg] * alpha + rs;
#pragma unroll
      for (int nt = 0; nt < 4; ++nt) o[nt][reg] *= alpha;
    }

    __hip_bfloat16* Pw = &Ps[w][0];
#pragma unroll
    for (int nt = 0; nt < 4; ++nt)
#pragma unroll
      for (int reg = 0; reg < 4; ++reg)
        Pw[(quad * 4 + reg) * 80 + nt * 16 + lrow] = __float2bfloat16(p[nt][reg]);
    __syncthreads();  // P (and ordering) visible

    s8v ap0 = *(const s8v*)(Pw + lrow * 80 + quad * 8);
    s8v ap1 = *(const s8v*)(Pw + lrow * 80 + 32 + quad * 8);
#pragma unroll
    for (int nt = 0; nt < 4; ++nt) {
      s8v bv0 = *(const s8v*)(Vs + (nt * 16 + lrow) * 64 + quad * 8);
      s8v bv1 = *(const s8v*)(Vs + (nt * 16 + lrow) * 64 + 32 + quad * 8);
      o[nt] = __builtin_amdgcn_mfma_f32_16x16x32_bf16(ap0, bv0, o[nt], 0, 0, 0);
      o[nt] = __builtin_amdgcn_mfma_f32_16x16x32_bf16(ap1, bv1, o[nt], 0, 0, 0);
    }
  }

  float* op = out + ((size_t)(bh >> 4) * 2048 + (size_t)qi * 64 + w * 16) * 1024 + (bh & 15) * 64;
#pragma unroll
  for (int nt = 0; nt < 4; ++nt)
#pragma unroll
    for (int reg = 0; reg < 4; ++reg)
      op[(size_t)(quad * 4 + reg) * 1024 + nt * 16 + lrow] = o[nt][reg] / l_r[reg];
}

extern "C" void kernel_launch(void* const* d_in, const int* in_sizes, int n_in,
                              void* d_out, int out_size, void* d_ws, size_t ws_size,
                              hipStream_t stream) {
  const float* x = (const float*)d_in[0];     // [2,2048,1024]
  const float* W = (const float*)d_in[1];     // [1024,3072]
  const float* bias = (const float*)d_in[2];  // [3072]
  float* out = (float*)d_out;                 // [2,2048,1024]

  char* ws = (char*)d_ws;
  __hip_bfloat16* xb = (__hip_bfloat16*)ws;                           // 8,388,608 B
  __hip_bfloat16* Wt = (__hip_bfloat16*)(ws + 8388608);               // 6,291,456 B
  __hip_bfloat16* y  = (__hip_bfloat16*)(ws + 8388608 + 6291456);     // 25,165,824 B
  __hip_bfloat16* Qg = (__hip_bfloat16*)(ws + 39845888);              // 8,388,608 B
  __hip_bfloat16* Kg = (__hip_bfloat16*)(ws + 48234496);              // 8,388,608 B
  __hip_bfloat16* Vt = (__hip_bfloat16*)(ws + 56623104);              // 8,388,608 B

  k_cvt_x<<<4096, 256, 0, stream>>>(x, xb);
  k_transpose_w<<<dim3(96, 32), 256, 0, stream>>>(W, Wt);
  k_gemm<<<dim3(24, 32), 256, 0, stream>>>(xb, Wt, bias, y);
  k_gather<<<768, 256, 0, stream>>>(y, Qg, Kg, Vt);
  k_attn<<<dim3(32, 32), 256, 0, stream>>>(Qg, Kg, Vt, out);
}